// Round 1
// baseline (835.635 us; speedup 1.0000x reference)
//
#include <hip/hip_runtime.h>
#include <math.h>

#define NN 50000
#define NE 800000
#define HEADS 4
#define HID 64
#define HD 256          // HEADS*HID flattened feature dim
#define NEG_SLOPE 0.2f
#define NCHUNK 49       // ceil(50000/1024)

// ---------------- CSR build ----------------
__global__ void count_kernel(const int* __restrict__ dst, int* __restrict__ cnt) {
    int e = blockIdx.x * 256 + threadIdx.x;
    if (e < NE) atomicAdd(&cnt[dst[e]], 1);
}

__global__ void chunk_sum_kernel(const int* __restrict__ cnt, int* __restrict__ csum, int n) {
    __shared__ int sdata[256];
    int base = blockIdx.x * 1024;
    int t = threadIdx.x;
    int s = 0;
    for (int i = t; i < 1024; i += 256) {
        int idx = base + i;
        if (idx < n) s += cnt[idx];
    }
    sdata[t] = s; __syncthreads();
    for (int off = 128; off > 0; off >>= 1) {
        if (t < off) sdata[t] += sdata[t + off];
        __syncthreads();
    }
    if (t == 0) csum[blockIdx.x] = sdata[0];
}

__global__ void chunk_scan_kernel(int* __restrict__ csum, int nchunks) {
    if (threadIdx.x == 0 && blockIdx.x == 0) {
        int run = 0;
        for (int i = 0; i < nchunks; i++) { int v = csum[i]; csum[i] = run; run += v; }
    }
}

__global__ void rowptr_kernel(const int* __restrict__ cnt, const int* __restrict__ coff,
                              int* __restrict__ rowptr, int n) {
    __shared__ int buf[1024];
    int t = threadIdx.x;
    int idx = blockIdx.x * 1024 + t;
    int v = (idx < n) ? cnt[idx] : 0;
    buf[t] = v; __syncthreads();
    for (int off = 1; off < 1024; off <<= 1) {
        int tmp = (t >= off) ? buf[t - off] : 0;
        __syncthreads();
        buf[t] += tmp;
        __syncthreads();
    }
    int excl = buf[t] - v + coff[blockIdx.x];
    if (idx < n) rowptr[idx] = excl;
    if (idx == n - 1) rowptr[n] = excl + v;
}

__global__ void scatter_kernel(const int* __restrict__ src, const int* __restrict__ dst,
                               const int* __restrict__ rowptr, int* __restrict__ cursor,
                               int* __restrict__ csr_src) {
    int e = blockIdx.x * 256 + threadIdx.x;
    if (e < NE) {
        int d = dst[e];
        int p = rowptr[d] + atomicAdd(&cursor[d], 1);
        csr_src[p] = src[e];
    }
}

// ---------------- SGEMM: H[N,256] = X[N,K] @ W[K,256] ----------------
__global__ __launch_bounds__(256) void sgemm_kernel(const float* __restrict__ X,
                                                    const float* __restrict__ W,
                                                    float* __restrict__ H, int K) {
    __shared__ float As[16][68];
    __shared__ float Bs[16][64];
    int tid = threadIdx.x;
    int rowBase = blockIdx.x * 64;
    int n0 = blockIdx.y * 64;
    float acc[4][4] = {};
    int lr = tid >> 2, kq = tid & 3;      // A load: row lr (0..63), k quad kq
    int bk = tid >> 4, bn = tid & 15;     // B load: k row bk (0..15), col quad bn
    int tm = (tid & 15) * 4, tn = (tid >> 4) * 4;

    for (int k0 = 0; k0 < K; k0 += 16) {
        float4 a4 = make_float4(0.f, 0.f, 0.f, 0.f);
        int arow = rowBase + lr;
        if (arow < NN) a4 = *(const float4*)&X[(long)arow * K + k0 + kq * 4];
        As[kq * 4 + 0][lr] = a4.x;
        As[kq * 4 + 1][lr] = a4.y;
        As[kq * 4 + 2][lr] = a4.z;
        As[kq * 4 + 3][lr] = a4.w;
        float4 b4 = *(const float4*)&W[(long)(k0 + bk) * HD + n0 + bn * 4];
        *(float4*)&Bs[bk][bn * 4] = b4;
        __syncthreads();
#pragma unroll
        for (int kk = 0; kk < 16; kk++) {
            float4 a = *(const float4*)&As[kk][tm];
            float4 b = *(const float4*)&Bs[kk][tn];
            float av[4] = {a.x, a.y, a.z, a.w};
            float bv[4] = {b.x, b.y, b.z, b.w};
#pragma unroll
            for (int i = 0; i < 4; i++)
#pragma unroll
                for (int j = 0; j < 4; j++) acc[i][j] += av[i] * bv[j];
        }
        __syncthreads();
    }
#pragma unroll
    for (int i = 0; i < 4; i++) {
        int r = rowBase + tm + i;
        if (r < NN) {
            float4 o = make_float4(acc[i][0], acc[i][1], acc[i][2], acc[i][3]);
            *(float4*)&H[(long)r * HD + n0 + tn] = o;
        }
    }
}

// ---------------- el/er: one wave per node ----------------
__global__ __launch_bounds__(256) void el_er_kernel(const float* __restrict__ H,
                                                    const float* __restrict__ al,
                                                    const float* __restrict__ ar,
                                                    float* __restrict__ el,
                                                    float* __restrict__ er) {
    int wave = threadIdx.x >> 6, lane = threadIdx.x & 63;
    int n = blockIdx.x * 4 + wave;
    if (n >= NN) return;
    float4 h4 = *(const float4*)&H[(long)n * HD + lane * 4];
    float4 a4 = *(const float4*)&al[lane * 4];
    float4 r4 = *(const float4*)&ar[lane * 4];
    float pl = h4.x * a4.x + h4.y * a4.y + h4.z * a4.z + h4.w * a4.w;
    float pr = h4.x * r4.x + h4.y * r4.y + h4.z * r4.z + h4.w * r4.w;
#pragma unroll
    for (int off = 1; off < 16; off <<= 1) {
        pl += __shfl_xor(pl, off);
        pr += __shfl_xor(pr, off);
    }
    if ((lane & 15) == 0) {
        el[n * 4 + (lane >> 4)] = pl;
        er[n * 4 + (lane >> 4)] = pr;
    }
}

// ---------------- GAT per-node softmax+aggregate: one wave per node ----------------
__device__ __forceinline__ float lrelu(float x) { return x > 0.f ? x : NEG_SLOPE * x; }

template <int FINAL>
__global__ __launch_bounds__(256) void gat_node_kernel(
    const float* __restrict__ H, const float* __restrict__ el, const float* __restrict__ er,
    const int* __restrict__ rowptr, const int* __restrict__ csr_src,
    float* __restrict__ out, const float* __restrict__ Wout, const float* __restrict__ bout,
    float* __restrict__ final_out) {
    int wave = threadIdx.x >> 6, lane = threadIdx.x & 63;
    int v = blockIdx.x * 4 + wave;
    if (v >= NN) return;
    int beg = rowptr[v], end = rowptr[v + 1];

    int ha = lane & 3;    // head for passes 1-2
    int le = lane >> 2;   // local edge slot 0..15
    float er_v = er[v * 4 + ha];

    // pass 1: per-head max
    float m = -INFINITY;
    for (int c = beg; c < end; c += 16) {
        int idx = c + le;
        if (idx < end) {
            int s = csr_src[idx];
            float e = lrelu(el[s * 4 + ha] + er_v);
            m = fmaxf(m, e);
        }
    }
    m = fmaxf(m, __shfl_xor(m, 4));
    m = fmaxf(m, __shfl_xor(m, 8));
    m = fmaxf(m, __shfl_xor(m, 16));
    m = fmaxf(m, __shfl_xor(m, 32));

    // pass 2: per-head exp-sum
    float ssum = 0.f;
    for (int c = beg; c < end; c += 16) {
        int idx = c + le;
        if (idx < end) {
            int s = csr_src[idx];
            float e = lrelu(el[s * 4 + ha] + er_v);
            ssum += __expf(e - m);
        }
    }
    ssum += __shfl_xor(ssum, 4);
    ssum += __shfl_xor(ssum, 8);
    ssum += __shfl_xor(ssum, 16);
    ssum += __shfl_xor(ssum, 32);

    // pass 3: aggregate. lane covers flat dims [lane*4, lane*4+4) -> head hh = lane>>4
    int hh = lane >> 4;
    float m_h = __shfl(m, hh);     // lane h (h<4) holds head h's stats
    float d_h = __shfl(ssum, hh);
    float inv = 1.0f / (d_h + 1e-9f);
    float er_h = er[v * 4 + hh];

    float4 acc = make_float4(0.f, 0.f, 0.f, 0.f);
    for (int idx = beg; idx < end; ++idx) {
        int s = csr_src[idx];
        float e = lrelu(el[s * 4 + hh] + er_h);
        float a = __expf(e - m_h) * inv;
        float4 hv = *(const float4*)&H[(long)s * HD + lane * 4];
        acc.x += hv.x * a;
        acc.y += hv.y * a;
        acc.z += hv.z * a;
        acc.w += hv.w * a;
    }
    // elu
    acc.x = acc.x > 0.f ? acc.x : expm1f(acc.x);
    acc.y = acc.y > 0.f ? acc.y : expm1f(acc.y);
    acc.z = acc.z > 0.f ? acc.z : expm1f(acc.z);
    acc.w = acc.w > 0.f ? acc.w : expm1f(acc.w);

    if (!FINAL) {
        *(float4*)&out[(long)v * HD + lane * 4] = acc;
    } else {
        // mean over heads (lanes l, l^16, l^32 hold same d-range, different head)
        acc.x += __shfl_xor(acc.x, 16); acc.x += __shfl_xor(acc.x, 32);
        acc.y += __shfl_xor(acc.y, 16); acc.y += __shfl_xor(acc.y, 32);
        acc.z += __shfl_xor(acc.z, 16); acc.z += __shfl_xor(acc.z, 32);
        acc.w += __shfl_xor(acc.w, 16); acc.w += __shfl_xor(acc.w, 32);
        float4 w4 = *(const float4*)&Wout[(lane & 15) * 4];
        float p = 0.25f * (acc.x * w4.x + acc.y * w4.y + acc.z * w4.z + acc.w * w4.w);
        p += __shfl_xor(p, 1);
        p += __shfl_xor(p, 2);
        p += __shfl_xor(p, 4);
        p += __shfl_xor(p, 8);
        if (lane == 0) final_out[v] = fmaxf(p + bout[0], 0.f);
    }
}

extern "C" void kernel_launch(void* const* d_in, const int* in_sizes, int n_in,
                              void* d_out, int out_size, void* d_ws, size_t ws_size,
                              hipStream_t stream) {
    const float* x    = (const float*)d_in[0];
    const int*   src  = (const int*)d_in[1];
    const int*   dst  = (const int*)d_in[2];
    const float* W0   = (const float*)d_in[3];
    const float* al0  = (const float*)d_in[4];
    const float* ar0  = (const float*)d_in[5];
    const float* W1   = (const float*)d_in[6];
    const float* al1  = (const float*)d_in[7];
    const float* ar1  = (const float*)d_in[8];
    const float* W2   = (const float*)d_in[9];
    const float* al2  = (const float*)d_in[10];
    const float* ar2  = (const float*)d_in[11];
    const float* Wout = (const float*)d_in[12];
    const float* bout = (const float*)d_in[13];
    float* outp = (float*)d_out;

    char* ws = (char*)d_ws;
    size_t off = 0;
    auto carve = [&](size_t n) -> char* {
        char* p = ws + off;
        off += (n + 255) & ~(size_t)255;
        return p;
    };
    float* h_buf   = (float*)carve((size_t)NN * HD * 4);
    float* x_buf   = (float*)carve((size_t)NN * HD * 4);
    float* el      = (float*)carve((size_t)NN * HEADS * 4);
    float* er      = (float*)carve((size_t)NN * HEADS * 4);
    int*   cnt     = (int*)carve((size_t)NN * 4);
    int*   rowptr  = (int*)carve((size_t)(NN + 1) * 4);
    int*   csr_src = (int*)carve((size_t)NE * 4);
    int*   csum    = (int*)carve(64 * 4);

    // ---- build dst-CSR (same work every call) ----
    hipMemsetAsync(cnt, 0, (size_t)NN * 4, stream);
    count_kernel<<<(NE + 255) / 256, 256, 0, stream>>>(dst, cnt);
    chunk_sum_kernel<<<NCHUNK, 256, 0, stream>>>(cnt, csum, NN);
    chunk_scan_kernel<<<1, 64, 0, stream>>>(csum, NCHUNK);
    rowptr_kernel<<<NCHUNK, 1024, 0, stream>>>(cnt, csum, rowptr, NN);
    hipMemsetAsync(cnt, 0, (size_t)NN * 4, stream);
    scatter_kernel<<<(NE + 255) / 256, 256, 0, stream>>>(src, dst, rowptr, cnt, csr_src);

    dim3 gGemm((NN + 63) / 64, HD / 64);
    int gNode = (NN + 3) / 4;

    // ---- layer 0 ----
    sgemm_kernel<<<gGemm, 256, 0, stream>>>(x, W0, h_buf, 128);
    el_er_kernel<<<gNode, 256, 0, stream>>>(h_buf, al0, ar0, el, er);
    gat_node_kernel<0><<<gNode, 256, 0, stream>>>(h_buf, el, er, rowptr, csr_src,
                                                  x_buf, nullptr, nullptr, nullptr);
    // ---- layer 1 ----
    sgemm_kernel<<<gGemm, 256, 0, stream>>>(x_buf, W1, h_buf, 256);
    el_er_kernel<<<gNode, 256, 0, stream>>>(h_buf, al1, ar1, el, er);
    gat_node_kernel<0><<<gNode, 256, 0, stream>>>(h_buf, el, er, rowptr, csr_src,
                                                  x_buf, nullptr, nullptr, nullptr);
    // ---- layer 2 (final: fused elu + head-mean + Wout + relu) ----
    sgemm_kernel<<<gGemm, 256, 0, stream>>>(x_buf, W2, h_buf, 256);
    el_er_kernel<<<gNode, 256, 0, stream>>>(h_buf, al2, ar2, el, er);
    gat_node_kernel<1><<<gNode, 256, 0, stream>>>(h_buf, el, er, rowptr, csr_src,
                                                  nullptr, Wout, bout, outp);
}

// Round 2
// 807.246 us; speedup vs baseline: 1.0352x; 1.0352x over previous
//
#include <hip/hip_runtime.h>
#include <math.h>

#define NN 50000
#define NE 800000
#define HEADS 4
#define HID 64
#define HD 256          // HEADS*HID flattened feature dim
#define NEG_SLOPE 0.2f
#define NCHUNK 49       // ceil(50000/1024)

// ---------------- CSR build ----------------
__global__ void count_kernel(const int* __restrict__ dst, int* __restrict__ cnt) {
    int e = blockIdx.x * 256 + threadIdx.x;
    if (e < NE) atomicAdd(&cnt[dst[e]], 1);
}

__global__ void chunk_sum_kernel(const int* __restrict__ cnt, int* __restrict__ csum, int n) {
    __shared__ int sdata[256];
    int base = blockIdx.x * 1024;
    int t = threadIdx.x;
    int s = 0;
    for (int i = t; i < 1024; i += 256) {
        int idx = base + i;
        if (idx < n) s += cnt[idx];
    }
    sdata[t] = s; __syncthreads();
    for (int off = 128; off > 0; off >>= 1) {
        if (t < off) sdata[t] += sdata[t + off];
        __syncthreads();
    }
    if (t == 0) csum[blockIdx.x] = sdata[0];
}

__global__ void chunk_scan_kernel(int* __restrict__ csum, int nchunks) {
    if (threadIdx.x == 0 && blockIdx.x == 0) {
        int run = 0;
        for (int i = 0; i < nchunks; i++) { int v = csum[i]; csum[i] = run; run += v; }
    }
}

__global__ void rowptr_kernel(const int* __restrict__ cnt, const int* __restrict__ coff,
                              int* __restrict__ rowptr, int n) {
    __shared__ int buf[1024];
    int t = threadIdx.x;
    int idx = blockIdx.x * 1024 + t;
    int v = (idx < n) ? cnt[idx] : 0;
    buf[t] = v; __syncthreads();
    for (int off = 1; off < 1024; off <<= 1) {
        int tmp = (t >= off) ? buf[t - off] : 0;
        __syncthreads();
        buf[t] += tmp;
        __syncthreads();
    }
    int excl = buf[t] - v + coff[blockIdx.x];
    if (idx < n) rowptr[idx] = excl;
    if (idx == n - 1) rowptr[n] = excl + v;
}

__global__ void scatter_kernel(const int* __restrict__ src, const int* __restrict__ dst,
                               const int* __restrict__ rowptr, int* __restrict__ cursor,
                               int* __restrict__ csr_src) {
    int e = blockIdx.x * 256 + threadIdx.x;
    if (e < NE) {
        int d = dst[e];
        int p = rowptr[d] + atomicAdd(&cursor[d], 1);
        csr_src[p] = src[e];
    }
}

// ---------------- SGEMM: H[N,256] = X[N,K] @ W[K,256] ----------------
// 128x64 block tile, 8x4 microtile (row groups tm and tm+64 -> conflict-free b128)
__global__ __launch_bounds__(256) void sgemm_kernel(const float* __restrict__ X,
                                                    const float* __restrict__ W,
                                                    float* __restrict__ H, int K) {
    __shared__ float As[16][128];
    __shared__ float Bs[16][64];
    int tid = threadIdx.x;
    int rowBase = blockIdx.x * 128;
    int n0 = blockIdx.y * 64;
    float acc[8][4] = {};

    int ar = tid >> 1, kh = (tid & 1) * 8;   // A: row ar (0..127), k-half kh
    int bk = tid >> 4, bn = (tid & 15) * 4;  // B: k row bk, col quad bn
    int tm = (tid & 15) * 4;                 // micro rows tm..tm+3, 64+tm..64+tm+3
    int tn = (tid >> 4) * 4;                 // micro cols

    for (int k0 = 0; k0 < K; k0 += 16) {
        float4 a0 = make_float4(0.f, 0.f, 0.f, 0.f);
        float4 a1 = make_float4(0.f, 0.f, 0.f, 0.f);
        int arow = rowBase + ar;
        if (arow < NN) {
            const float* xp = &X[(long)arow * K + k0 + kh];
            a0 = *(const float4*)xp;
            a1 = *(const float4*)(xp + 4);
        }
        As[kh + 0][ar] = a0.x; As[kh + 1][ar] = a0.y;
        As[kh + 2][ar] = a0.z; As[kh + 3][ar] = a0.w;
        As[kh + 4][ar] = a1.x; As[kh + 5][ar] = a1.y;
        As[kh + 6][ar] = a1.z; As[kh + 7][ar] = a1.w;
        *(float4*)&Bs[bk][bn] = *(const float4*)&W[(long)(k0 + bk) * HD + n0 + bn];
        __syncthreads();
#pragma unroll
        for (int kk = 0; kk < 16; kk++) {
            float4 aA = *(const float4*)&As[kk][tm];
            float4 aB = *(const float4*)&As[kk][64 + tm];
            float4 b  = *(const float4*)&Bs[kk][tn];
            float av[8] = {aA.x, aA.y, aA.z, aA.w, aB.x, aB.y, aB.z, aB.w};
            float bv[4] = {b.x, b.y, b.z, b.w};
#pragma unroll
            for (int i = 0; i < 8; i++)
#pragma unroll
                for (int j = 0; j < 4; j++) acc[i][j] += av[i] * bv[j];
        }
        __syncthreads();
    }
#pragma unroll
    for (int g = 0; g < 2; g++) {
#pragma unroll
        for (int i = 0; i < 4; i++) {
            int r = rowBase + g * 64 + tm + i;
            if (r < NN) {
                float4 o = make_float4(acc[g * 4 + i][0], acc[g * 4 + i][1],
                                       acc[g * 4 + i][2], acc[g * 4 + i][3]);
                *(float4*)&H[(long)r * HD + n0 + tn] = o;
            }
        }
    }
}

// ---------------- el/er: one wave per node ----------------
__global__ __launch_bounds__(256) void el_er_kernel(const float* __restrict__ H,
                                                    const float* __restrict__ al,
                                                    const float* __restrict__ ar,
                                                    float* __restrict__ el,
                                                    float* __restrict__ er) {
    int wave = threadIdx.x >> 6, lane = threadIdx.x & 63;
    int n = blockIdx.x * 4 + wave;
    if (n >= NN) return;
    float4 h4 = *(const float4*)&H[(long)n * HD + lane * 4];
    float4 a4 = *(const float4*)&al[lane * 4];
    float4 r4 = *(const float4*)&ar[lane * 4];
    float pl = h4.x * a4.x + h4.y * a4.y + h4.z * a4.z + h4.w * a4.w;
    float pr = h4.x * r4.x + h4.y * r4.y + h4.z * r4.z + h4.w * r4.w;
#pragma unroll
    for (int off = 1; off < 16; off <<= 1) {
        pl += __shfl_xor(pl, off);
        pr += __shfl_xor(pr, off);
    }
    if ((lane & 15) == 0) {
        el[n * 4 + (lane >> 4)] = pl;
        er[n * 4 + (lane >> 4)] = pr;
    }
}

// ---------------- GAT per-node: single-pass flash softmax + aggregate ----------------
__device__ __forceinline__ float lrelu(float x) { return x > 0.f ? x : NEG_SLOPE * x; }

template <int FINAL>
__global__ __launch_bounds__(256) void gat_node_kernel(
    const float* __restrict__ H, const float* __restrict__ el, const float* __restrict__ er,
    const int* __restrict__ rowptr, const int* __restrict__ csr_src,
    float* __restrict__ out, const float* __restrict__ Wout, const float* __restrict__ bout,
    float* __restrict__ final_out) {
    int wave = threadIdx.x >> 6, lane = threadIdx.x & 63;
    int v = blockIdx.x * 4 + wave;
    if (v >= NN) return;
    int beg = rowptr[v], end = rowptr[v + 1];

    int hh = lane >> 4;                    // head for this lane's feature slice
    float er_h = er[v * 4 + hh];

    float m = -INFINITY;
    float ssum = 0.f;
    float4 acc = make_float4(0.f, 0.f, 0.f, 0.f);

    int idx = beg;
    // unroll-2: two independent gather chains in flight
    for (; idx + 2 <= end; idx += 2) {
        int s0 = csr_src[idx];
        int s1 = csr_src[idx + 1];
        float el0 = el[s0 * 4 + hh];
        float el1 = el[s1 * 4 + hh];
        float4 h0 = *(const float4*)&H[(long)s0 * HD + lane * 4];
        float4 h1 = *(const float4*)&H[(long)s1 * HD + lane * 4];
        float e0 = lrelu(el0 + er_h);
        float e1 = lrelu(el1 + er_h);
        float mn = fmaxf(m, fmaxf(e0, e1));
        float sc = __expf(m - mn);
        float w0 = __expf(e0 - mn);
        float w1 = __expf(e1 - mn);
        ssum = ssum * sc + w0 + w1;
        acc.x = acc.x * sc + w0 * h0.x + w1 * h1.x;
        acc.y = acc.y * sc + w0 * h0.y + w1 * h1.y;
        acc.z = acc.z * sc + w0 * h0.z + w1 * h1.z;
        acc.w = acc.w * sc + w0 * h0.w + w1 * h1.w;
        m = mn;
    }
    if (idx < end) {
        int s0 = csr_src[idx];
        float el0 = el[s0 * 4 + hh];
        float4 h0 = *(const float4*)&H[(long)s0 * HD + lane * 4];
        float e0 = lrelu(el0 + er_h);
        float mn = fmaxf(m, e0);
        float sc = __expf(m - mn);
        float w0 = __expf(e0 - mn);
        ssum = ssum * sc + w0;
        acc.x = acc.x * sc + w0 * h0.x;
        acc.y = acc.y * sc + w0 * h0.y;
        acc.z = acc.z * sc + w0 * h0.z;
        acc.w = acc.w * sc + w0 * h0.w;
    }

    float inv = 1.0f / (ssum + 1e-9f);
    acc.x *= inv; acc.y *= inv; acc.z *= inv; acc.w *= inv;

    // elu
    acc.x = acc.x > 0.f ? acc.x : expm1f(acc.x);
    acc.y = acc.y > 0.f ? acc.y : expm1f(acc.y);
    acc.z = acc.z > 0.f ? acc.z : expm1f(acc.z);
    acc.w = acc.w > 0.f ? acc.w : expm1f(acc.w);

    if (!FINAL) {
        *(float4*)&out[(long)v * HD + lane * 4] = acc;
    } else {
        // mean over heads (lanes l, l^16, l^32 hold same d-range, different head)
        acc.x += __shfl_xor(acc.x, 16); acc.x += __shfl_xor(acc.x, 32);
        acc.y += __shfl_xor(acc.y, 16); acc.y += __shfl_xor(acc.y, 32);
        acc.z += __shfl_xor(acc.z, 16); acc.z += __shfl_xor(acc.z, 32);
        acc.w += __shfl_xor(acc.w, 16); acc.w += __shfl_xor(acc.w, 32);
        float4 w4 = *(const float4*)&Wout[(lane & 15) * 4];
        float p = 0.25f * (acc.x * w4.x + acc.y * w4.y + acc.z * w4.z + acc.w * w4.w);
        p += __shfl_xor(p, 1);
        p += __shfl_xor(p, 2);
        p += __shfl_xor(p, 4);
        p += __shfl_xor(p, 8);
        if (lane == 0) final_out[v] = fmaxf(p + bout[0], 0.f);
    }
}

extern "C" void kernel_launch(void* const* d_in, const int* in_sizes, int n_in,
                              void* d_out, int out_size, void* d_ws, size_t ws_size,
                              hipStream_t stream) {
    const float* x    = (const float*)d_in[0];
    const int*   src  = (const int*)d_in[1];
    const int*   dst  = (const int*)d_in[2];
    const float* W0   = (const float*)d_in[3];
    const float* al0  = (const float*)d_in[4];
    const float* ar0  = (const float*)d_in[5];
    const float* W1   = (const float*)d_in[6];
    const float* al1  = (const float*)d_in[7];
    const float* ar1  = (const float*)d_in[8];
    const float* W2   = (const float*)d_in[9];
    const float* al2  = (const float*)d_in[10];
    const float* ar2  = (const float*)d_in[11];
    const float* Wout = (const float*)d_in[12];
    const float* bout = (const float*)d_in[13];
    float* outp = (float*)d_out;

    char* ws = (char*)d_ws;
    size_t off = 0;
    auto carve = [&](size_t n) -> char* {
        char* p = ws + off;
        off += (n + 255) & ~(size_t)255;
        return p;
    };
    float* h_buf   = (float*)carve((size_t)NN * HD * 4);
    float* x_buf   = (float*)carve((size_t)NN * HD * 4);
    float* el      = (float*)carve((size_t)NN * HEADS * 4);
    float* er      = (float*)carve((size_t)NN * HEADS * 4);
    int*   cnt     = (int*)carve((size_t)NN * 4);
    int*   rowptr  = (int*)carve((size_t)(NN + 1) * 4);
    int*   csr_src = (int*)carve((size_t)NE * 4);
    int*   csum    = (int*)carve(64 * 4);

    // ---- build dst-CSR (same work every call) ----
    hipMemsetAsync(cnt, 0, (size_t)NN * 4, stream);
    count_kernel<<<(NE + 255) / 256, 256, 0, stream>>>(dst, cnt);
    chunk_sum_kernel<<<NCHUNK, 256, 0, stream>>>(cnt, csum, NN);
    chunk_scan_kernel<<<1, 64, 0, stream>>>(csum, NCHUNK);
    rowptr_kernel<<<NCHUNK, 1024, 0, stream>>>(cnt, csum, rowptr, NN);
    hipMemsetAsync(cnt, 0, (size_t)NN * 4, stream);
    scatter_kernel<<<(NE + 255) / 256, 256, 0, stream>>>(src, dst, rowptr, cnt, csr_src);

    dim3 gGemm((NN + 127) / 128, HD / 64);
    int gNode = (NN + 3) / 4;

    // ---- layer 0 ----
    sgemm_kernel<<<gGemm, 256, 0, stream>>>(x, W0, h_buf, 128);
    el_er_kernel<<<gNode, 256, 0, stream>>>(h_buf, al0, ar0, el, er);
    gat_node_kernel<0><<<gNode, 256, 0, stream>>>(h_buf, el, er, rowptr, csr_src,
                                                  x_buf, nullptr, nullptr, nullptr);
    // ---- layer 1 ----
    sgemm_kernel<<<gGemm, 256, 0, stream>>>(x_buf, W1, h_buf, 256);
    el_er_kernel<<<gNode, 256, 0, stream>>>(h_buf, al1, ar1, el, er);
    gat_node_kernel<0><<<gNode, 256, 0, stream>>>(h_buf, el, er, rowptr, csr_src,
                                                  x_buf, nullptr, nullptr, nullptr);
    // ---- layer 2 (final: fused elu + head-mean + Wout + relu) ----
    sgemm_kernel<<<gGemm, 256, 0, stream>>>(x_buf, W2, h_buf, 256);
    el_er_kernel<<<gNode, 256, 0, stream>>>(h_buf, al2, ar2, el, er);
    gat_node_kernel<1><<<gNode, 256, 0, stream>>>(h_buf, el, er, rowptr, csr_src,
                                                  nullptr, Wout, bout, outp);
}